// Round 9
// baseline (202.629 us; speedup 1.0000x reference)
//
#include <hip/hip_runtime.h>

// HierarchicalTimeAttention  B=4, T=4096, H=1024, D=4
// R9: 4-deep LDS ring GEMM (true T4): BK=32, 4 buffers (128KB), pipeline
// depth 3 K-steps, counted s_waitcnt vmcnt(8) (8 newer loads stay in flight
// across the barrier), ONE barrier per K-step, swizzle phys_g = g^((row>>1)&3)
// (2 lanes/bank = free), setprio around the 32-MFMA cluster.
// R8 baseline: GEMM 50.6us, MfmaUtil 25%, conflicts 0, drain-limited dbuf.
#define B_ 4
#define T_ 4096
#define H_ 1024
#define D_ 4
#define M_ (B_ * T_)          // 16384
#define OUT_MAIN (M_ * H_)    // 16,777,216 (f32 elements)

// ws (bytes), total ~40.3MB:
#define WS_BUF  0UL           // bf16 [M][H]: k -> kv -> o   (32MB)
#define WS_WK   33554432UL    // bf16 Wk,Wv,Wr,Wo contiguous [4][H][H] (8MB)
#define WS_LGW  41943040UL    // f32 softmax weights [M][4] (256KB)
#define WS_DEC  42205184UL    // f32 decayed_state0 [B][D][H] (64KB)

typedef __bf16 bf16x8 __attribute__((ext_vector_type(8)));
typedef unsigned short u16x4 __attribute__((ext_vector_type(4)));
typedef float f32x4 __attribute__((ext_vector_type(4)));

__device__ __forceinline__ float b2f(unsigned short u) {
    union { unsigned int i; float f; } c;
    c.i = ((unsigned int)u) << 16;
    return c.f;
}
__device__ __forceinline__ unsigned short f2b(float f) {
    union { float f; unsigned int i; } c;
    c.f = f;
    unsigned int x = c.i;
    unsigned int r = (x + 0x7FFFu + ((x >> 16) & 1u)) >> 16;  // RNE
    return (unsigned short)r;
}

#define BAR()  asm volatile("s_barrier" ::: "memory")
#define GLLDS(gsrc, ldst)                                                     \
    __builtin_amdgcn_global_load_lds(                                         \
        (const __attribute__((address_space(1))) unsigned int*)(gsrc),        \
        (__attribute__((address_space(3))) unsigned int*)(ldst), 16, 0, 0)

// ---------------------------------------------------------------------------
// f32 -> bf16 conversions
// ---------------------------------------------------------------------------
__global__ __launch_bounds__(256) void cvt_k(const float* __restrict__ s,
                                             unsigned short* __restrict__ d, int n4)
{
    int i = blockIdx.x * 256 + threadIdx.x;
    const int str = gridDim.x * 256;
    for (; i < n4; i += str) {
        const f32x4 v = ((const f32x4*)s)[i];
        u16x4 o;
        o[0] = f2b(v[0]); o[1] = f2b(v[1]); o[2] = f2b(v[2]); o[3] = f2b(v[3]);
        ((u16x4*)d)[i] = o;
    }
}

// 4 weight matrices in one dispatch: grid (1024, 4), dst contiguous [4][H][H]
__global__ __launch_bounds__(256) void cvtw_k(
    const float* __restrict__ s0, const float* __restrict__ s1,
    const float* __restrict__ s2, const float* __restrict__ s3,
    unsigned short* __restrict__ d)
{
    const int w = blockIdx.y;
    const float* s = (w == 0) ? s0 : (w == 1) ? s1 : (w == 2) ? s2 : s3;
    const int i = blockIdx.x * 256 + threadIdx.x;
    const f32x4 v = ((const f32x4*)s)[i];
    u16x4 o;
    o[0] = f2b(v[0]); o[1] = f2b(v[1]); o[2] = f2b(v[2]); o[3] = f2b(v[3]);
    ((u16x4*)(d + (size_t)w * (H_ * H_)))[i] = o;
}

// ---------------------------------------------------------------------------
// GEMM: C[16384][1024] = A[16384][1024] @ W[1024][1024]^T  (bf16, f32 acc)
// 256x256 tile, 8 waves (2Mx4N, 128x64/wave), BK=32, 4-buffer LDS ring
// (4 x 16KB per operand = 128KB total), pipeline depth 3 K-steps.
// Per K-step t: vmcnt(8) [wait ONLY buf-t's 4 loads; 8 newer stay in
// flight] -> s_barrier -> issue stage(t+3) [4 GLLDS -> buf (t+3)&3, which
// is (t-1)&3: safe, barrier certified all step-(t-1) ds_reads done] ->
// 12x ds_read_b128 -> setprio(1) + 32 MFMA + setprio(0).
// Swizzle (BK=32 rows = 4 granules of 16B): phys_g = g ^ ((row>>1)&3);
// read lanes spread 2/bank (free); staged via inverse-swizzled global src.
//   A/B frag: row(col)=lane&15, k=8*(lane>>4)+i ; C/D: col=lane&15,
//   row=4*(lane>>4)+reg  [verified r2==r4 pipeline agreement]
// EPI 0: C = bf16(acc)        EPI 1: C = bf16(acc * C)   (in-place)
// EPI 2: C = bf16(sigmoid(acc)*(lw.dec + wsum*C))        (in-place)
// EPI 3: outf = acc (f32)
// ---------------------------------------------------------------------------
template <int EPI>
__global__ __launch_bounds__(512, 2) void gemm4r(
    const unsigned short* __restrict__ A,
    const unsigned short* __restrict__ Wt,
    unsigned short* C,
    float* __restrict__ outf,
    const float* __restrict__ lgw,
    const float* __restrict__ dec)
{
    __shared__ __align__(16) unsigned short As[4 * 8192];   // 4 bufs x 256x32
    __shared__ __align__(16) unsigned short Bs[4 * 8192];

    const int tid  = threadIdx.x;
    const int wid  = tid >> 6;        // 0..7
    const int lane = tid & 63;
    const int l15  = lane & 15;
    const int q    = lane >> 4;       // 0..3 (k granule)
    const int wrow = wid >> 2;        // 0..1  (128-row half)
    const int wcol = wid & 3;         // 0..3  (64-col quarter)
    const int brow = blockIdx.x * 256;
    const int bcol = blockIdx.y * 256;

    // --- staging addresses: thread stages granule G = i*512+tid (i=0,1)
    // row = i*128 + (tid>>2), phys g = tid&3, logical g = phys ^ ((row>>1)&3)
    const int lgst = (tid & 3) ^ ((tid >> 3) & 3);
    const int offA0 = (brow + (tid >> 2)) * 1024 + lgst * 8;
    const int offB0 = (bcol + (tid >> 2)) * 1024 + lgst * 8;
    const int dst0 = tid * 8;           // elem offset in buffer (granule G*8)
    const int dst1 = 4096 + tid * 8;

    // --- ds_read offsets (elements within one 8192-elem buffer)
    const int gx = (q ^ ((l15 >> 1) & 3)) * 8;
    int aoff[8], boff[4];
#pragma unroll
    for (int mi = 0; mi < 8; ++mi) aoff[mi] = (wrow * 128 + mi * 16 + l15) * 32 + gx;
#pragma unroll
    for (int ni = 0; ni < 4; ++ni) boff[ni] = (wcol * 64 + ni * 16 + l15) * 32 + gx;

    f32x4 acc[8][4];
#pragma unroll
    for (int i = 0; i < 8; ++i)
#pragma unroll
        for (int j = 0; j < 4; ++j)
            acc[i][j] = (f32x4){0.f, 0.f, 0.f, 0.f};

    auto stage = [&](int bo, int kk) {
        GLLDS(A  + offA0 + kk,              As + bo + dst0);
        GLLDS(A  + offA0 + 128 * 1024 + kk, As + bo + dst1);
        GLLDS(Wt + offB0 + kk,              Bs + bo + dst0);
        GLLDS(Wt + offB0 + 128 * 1024 + kk, Bs + bo + dst1);
    };
    auto compute = [&](int bo) {
        bf16x8 aR[8], bR[4];
#pragma unroll
        for (int mi = 0; mi < 8; ++mi) aR[mi] = *(const bf16x8*)&As[bo + aoff[mi]];
#pragma unroll
        for (int ni = 0; ni < 4; ++ni) bR[ni] = *(const bf16x8*)&Bs[bo + boff[ni]];
        __builtin_amdgcn_s_setprio(1);
#pragma unroll
        for (int mi = 0; mi < 8; ++mi)
#pragma unroll
            for (int ni = 0; ni < 4; ++ni)
                acc[mi][ni] = __builtin_amdgcn_mfma_f32_16x16x32_bf16(
                    aR[mi], bR[ni], acc[mi][ni], 0, 0, 0);
        __builtin_amdgcn_s_setprio(0);
    };

    // --- prologue: fill pipeline 3 deep (buffers 0,1,2 <- steps 0,1,2)
    stage(0,     0);
    stage(8192,  32);
    stage(16384, 64);

    // --- main: t = 0..27 (4-step unroll, all with stage(t+3))
#pragma unroll 1
    for (int tb = 0; tb < 28; tb += 4) {
        const int kk3 = (tb + 3) * 32;
        asm volatile("s_waitcnt vmcnt(8)" ::: "memory");
        BAR();
        stage(24576, kk3);            compute(0);
        asm volatile("s_waitcnt vmcnt(8)" ::: "memory");
        BAR();
        stage(0,     kk3 + 32);       compute(8192);
        asm volatile("s_waitcnt vmcnt(8)" ::: "memory");
        BAR();
        stage(8192,  kk3 + 64);       compute(16384);
        asm volatile("s_waitcnt vmcnt(8)" ::: "memory");
        BAR();
        stage(16384, kk3 + 96);       compute(24576);
    }
    // --- tail: t=28 (stage 31), 29, 30, 31
    asm volatile("s_waitcnt vmcnt(8)" ::: "memory");
    BAR();
    stage(24576, 31 * 32);            compute(0);
    asm volatile("s_waitcnt vmcnt(8)" ::: "memory");
    BAR();                            compute(8192);
    asm volatile("s_waitcnt vmcnt(4)" ::: "memory");
    BAR();                            compute(16384);
    asm volatile("s_waitcnt vmcnt(0)" ::: "memory");
    BAR();                            compute(24576);

    // ---- epilogue
    const int orow0 = brow + wrow * 128;
    const int ocol0 = bcol + wcol * 64;
    const int rbase = q * 4;
    if (EPI == 0) {
#pragma unroll
        for (int mi = 0; mi < 8; ++mi)
#pragma unroll
            for (int j = 0; j < 4; ++j) {
                const size_t r = (size_t)(orow0 + mi * 16 + rbase + j);
#pragma unroll
                for (int ni = 0; ni < 4; ++ni)
                    C[r * 1024 + (ocol0 + ni * 16 + l15)] = f2b(acc[mi][ni][j]);
            }
    } else if (EPI == 1) {
#pragma unroll
        for (int mi = 0; mi < 8; ++mi)
#pragma unroll
            for (int j = 0; j < 4; ++j) {
                const size_t r = (size_t)(orow0 + mi * 16 + rbase + j);
#pragma unroll
                for (int ni = 0; ni < 4; ++ni) {
                    const size_t idx = r * 1024 + (ocol0 + ni * 16 + l15);
                    C[idx] = f2b(acc[mi][ni][j] * b2f(C[idx]));
                }
            }
    } else if (EPI == 2) {
        const int b = brow >> 12;   // 256-row blocks never straddle a batch
        float dcol[4][4];
#pragma unroll
        for (int ni = 0; ni < 4; ++ni)
#pragma unroll
            for (int d = 0; d < 4; ++d)
                dcol[ni][d] = dec[b * (D_ * H_) + d * H_ + (ocol0 + ni * 16 + l15)];
#pragma unroll
        for (int mi = 0; mi < 8; ++mi)
#pragma unroll
            for (int j = 0; j < 4; ++j) {
                const int r = orow0 + mi * 16 + rbase + j;
                const f32x4 lw = *(const f32x4*)(lgw + (size_t)r * 4);
                const float wsum = lw[0] + lw[1] + lw[2] + lw[3];
#pragma unroll
                for (int ni = 0; ni < 4; ++ni) {
                    const size_t idx = (size_t)r * 1024 + (ocol0 + ni * 16 + l15);
                    const float rv = 1.0f / (1.0f + __expf(-acc[mi][ni][j]));
                    const float w  = lw[0] * dcol[ni][0] + lw[1] * dcol[ni][1]
                                   + lw[2] * dcol[ni][2] + lw[3] * dcol[ni][3]
                                   + wsum * b2f(C[idx]);
                    C[idx] = f2b(rv * w);
                }
            }
    } else {
#pragma unroll
        for (int mi = 0; mi < 8; ++mi)
#pragma unroll
            for (int j = 0; j < 4; ++j) {
                const size_t r = (size_t)(orow0 + mi * 16 + rbase + j);
#pragma unroll
                for (int ni = 0; ni < 4; ++ni)
                    outf[r * 1024 + (ocol0 + ni * 16 + l15)] = acc[mi][ni][j];
            }
    }
}

// ---------------------------------------------------------------------------
// lgw[row][0..3] = softmax(x @ Wl^T + bl), one wave per row, f32.
// ---------------------------------------------------------------------------
__global__ __launch_bounds__(256) void logits_k(
    const float* __restrict__ X, const float* __restrict__ Wl,
    const float* __restrict__ bl, float* __restrict__ lgw)
{
    const int wid  = threadIdx.x >> 6;
    const int lane = threadIdx.x & 63;
    const int row  = blockIdx.x * 4 + wid;
    const float* xp = X + (size_t)row * H_;

    float acc[D_] = {0.f, 0.f, 0.f, 0.f};
    for (int h = lane * 4; h < H_; h += 256) {
        const f32x4 xv = *(const f32x4*)(xp + h);
#pragma unroll
        for (int d = 0; d < D_; ++d) {
            const f32x4 wv = *(const f32x4*)(Wl + d * H_ + h);
            acc[d] += xv[0] * wv[0] + xv[1] * wv[1] + xv[2] * wv[2] + xv[3] * wv[3];
        }
    }
#pragma unroll
    for (int off = 32; off; off >>= 1)
#pragma unroll
        for (int d = 0; d < D_; ++d) acc[d] += __shfl_xor(acc[d], off, 64);

    if (lane == 0) {
        float l[D_];
#pragma unroll
        for (int d = 0; d < D_; ++d) l[d] = acc[d] + bl[d];
        const float mx = fmaxf(fmaxf(l[0], l[1]), fmaxf(l[2], l[3]));
        float e[D_], s = 0.f;
#pragma unroll
        for (int d = 0; d < D_; ++d) { e[d] = __expf(l[d] - mx); s += e[d]; }
        const float inv = 1.0f / s;
        f32x4 o;
#pragma unroll
        for (int d = 0; d < D_; ++d) o[d] = e[d] * inv;
        *(f32x4*)(lgw + (size_t)row * 4) = o;
    }
}

// ---------------------------------------------------------------------------
__global__ void decstate_k(const float* __restrict__ state,
                           const float* __restrict__ tdm,
                           float* __restrict__ dec)
{
    const int i = blockIdx.x * blockDim.x + threadIdx.x;
    if (i >= B_ * D_ * H_) return;
    const int dh = i & (D_ * H_ - 1);
    dec[i] = state[i] * __expf(-__expf(tdm[dh]));
}

// ---------------------------------------------------------------------------
// new_state[b,d,h] = dec[b,d,h] + k_last*v_last, all-f32 exact path.
// ---------------------------------------------------------------------------
__global__ __launch_bounds__(256) void newstate_k(
    const float* __restrict__ X, const float* __restrict__ Wk,
    const float* __restrict__ Wv, const float* __restrict__ dec,
    float* __restrict__ out2)
{
    const int wid  = threadIdx.x >> 6;
    const int lane = threadIdx.x & 63;
    const int row  = blockIdx.x * 4 + wid;   // 0..B*H-1
    const int b    = row >> 10;
    const int h    = row & (H_ - 1);
    const float* xp = X + ((size_t)(b * T_ + (T_ - 1))) * H_;

    float ak = 0.f, av = 0.f;
    for (int j = lane * 4; j < H_; j += 256) {
        const f32x4 xv = *(const f32x4*)(xp + j);
        const f32x4 wk = *(const f32x4*)(Wk + (size_t)h * H_ + j);
        const f32x4 wv = *(const f32x4*)(Wv + (size_t)h * H_ + j);
        ak += xv[0]*wk[0] + xv[1]*wk[1] + xv[2]*wk[2] + xv[3]*wk[3];
        av += xv[0]*wv[0] + xv[1]*wv[1] + xv[2]*wv[2] + xv[3]*wv[3];
    }
#pragma unroll
    for (int off = 32; off; off >>= 1) {
        ak += __shfl_xor(ak, off, 64);
        av += __shfl_xor(av, off, 64);
    }
    if (lane == 0) {
        const float kv = ak * av;
#pragma unroll
        for (int d = 0; d < D_; ++d)
            out2[(size_t)(b * D_ + d) * H_ + h] = dec[(b * D_ + d) * H_ + h] + kv;
    }
}

// ---------------------------------------------------------------------------
extern "C" void kernel_launch(void* const* d_in, const int* in_sizes, int n_in,
                              void* d_out, int out_size, void* d_ws, size_t ws_size,
                              hipStream_t stream)
{
    const float* x   = (const float*)d_in[0];
    const float* st  = (const float*)d_in[1];
    const float* tdm = (const float*)d_in[2];
    const float* Wl  = (const float*)d_in[3];
    const float* bl  = (const float*)d_in[4];
    const float* Wv  = (const float*)d_in[5];
    const float* Wk  = (const float*)d_in[6];
    const float* Wr  = (const float*)d_in[7];
    const float* Wo  = (const float*)d_in[8];
    float* out = (float*)d_out;                    // f32 output

    char* ws = (char*)d_ws;
    unsigned short* buf  = (unsigned short*)(ws + WS_BUF);   // k -> kv -> o
    unsigned short* wk_b = (unsigned short*)(ws + WS_WK);    // [4][H][H]: k,v,r,o
    unsigned short* wv_b = wk_b + 1 * (H_ * H_);
    unsigned short* wr_b = wk_b + 2 * (H_ * H_);
    unsigned short* wo_b = wk_b + 3 * (H_ * H_);
    float* lgw = (float*)(ws + WS_LGW);
    float* dec = (float*)(ws + WS_DEC);

    // bf16 x scratch inside d_out's f32 output-0 region; final GEMM
    // fully overwrites it afterwards.
    unsigned short* xb = (unsigned short*)out;

    // small f32 kernels (depend only on raw inputs)
    logits_k<<<M_ / 4, 256, 0, stream>>>(x, Wl, bl, lgw);
    decstate_k<<<(B_ * D_ * H_ + 255) / 256, 256, 0, stream>>>(st, tdm, dec);
    newstate_k<<<(B_ * H_) / 4, 256, 0, stream>>>(x, Wk, Wv, dec, out + OUT_MAIN);

    // conversions
    cvt_k<<<2048, 256, 0, stream>>>(x, xb, OUT_MAIN / 4);
    cvtw_k<<<dim3(1024, 4), 256, 0, stream>>>(Wk, Wv, Wr, Wo, wk_b);

    const dim3 g(M_ / 256, H_ / 256), blk(512);

    // buf = k
    hipLaunchKernelGGL((gemm4r<0>), g, blk, 0, stream, xb, wk_b, buf,
                       (float*)nullptr, (const float*)nullptr, (const float*)nullptr);
    // buf = kv
    hipLaunchKernelGGL((gemm4r<1>), g, blk, 0, stream, xb, wv_b, buf,
                       (float*)nullptr, (const float*)nullptr, (const float*)nullptr);
    // buf = o = sigmoid(x@Wr^T) * (lw.dec + wsum*kv)
    hipLaunchKernelGGL((gemm4r<2>), g, blk, 0, stream, xb, wr_b, buf,
                       (float*)nullptr, (const float*)lgw, (const float*)dec);
    // out = f32(o @ Wo^T)
    hipLaunchKernelGGL((gemm4r<3>), g, blk, 0, stream, buf, wo_b, (unsigned short*)nullptr,
                       out, (const float*)nullptr, (const float*)nullptr);
}